// Round 8
// baseline (121.644 us; speedup 1.0000x reference)
//
#include <hip/hip_runtime.h>

// RegionSelection: bilinear 2x upsample of attention map (8,1,80,80)->(8,1,160,160),
// per-batch rank-1921 threshold (k=int(0.3*6400)=1920, threshold=topv[:,k]),
// mask = up >= thr, weighted = local_feat*(mask+0.1).
// Outputs concatenated: weighted (8*256*160*160 fp32) then mask (8*160*160 fp32).
// d_ws: bit-packed mask, 400 ull per batch (1 bit per upsampled element).

#define NIN   6400    // 80*80
#define NUP   25600   // 160*160
#define KRANK 1921u   // (k+1)-th largest == topv[:, k]

typedef float f32x4 __attribute__((ext_vector_type(4)));

// Wave-parallel "find bin containing rank `rem_in` counting from the top" over
// NBINS histogram bins. Two-level: 64 chunk sums + shfl suffix-scan, then a
// parallel scan of the selected chunk's bins. No serial dependent-LDS chains.
// Executed by wave 0 (tid<64); writes {bin, remaining-within-bin} to s_bcast.
template <int NBINS>
__device__ inline void find_bin(const unsigned* s_hist, unsigned rem_in,
                                unsigned* s_bcast, int tid)
{
    constexpr int CHUNK = NBINS / 64;
    if (tid < 64) {
        const int lane = tid;
        unsigned csum = 0;
        #pragma unroll
        for (int k = 0; k < CHUNK; ++k) csum += s_hist[lane * CHUNK + k];
        unsigned suff = csum;                     // suffix sum: suff[l] = sum csum[l..63]
        #pragma unroll
        for (int off = 1; off < 64; off <<= 1) {
            unsigned o = __shfl_down(suff, off);
            if (lane + off < 64) suff += o;
        }
        unsigned suff_next = __shfl_down(suff, 1);
        if (lane == 63) suff_next = 0;
        const bool hit = (suff >= rem_in) & (suff_next < rem_in);  // exactly one lane
        unsigned long long bmask = __ballot(hit);
        const int src = (int)__builtin_ctzll(bmask);
        const unsigned r_chunk = __shfl(rem_in - suff_next, src);  // rank within chunk
        const int      cbase   = src * CHUNK;
        unsigned h = (lane < CHUNK) ? s_hist[cbase + lane] : 0u;
        unsigned ssum = h;
        #pragma unroll
        for (int off = 1; off < CHUNK; off <<= 1) {
            unsigned o = __shfl_down(ssum, off);
            if (lane + off < CHUNK) ssum += o;
        }
        unsigned ssum_next = __shfl_down(ssum, 1);
        if (lane >= CHUNK - 1) ssum_next = 0;
        const bool hit2 = (lane < CHUNK) & (ssum >= r_chunk) & (ssum_next < r_chunk);
        if (hit2) {
            s_bcast[0] = (unsigned)(cbase + lane);
            s_bcast[1] = r_chunk - ssum_next;
        }
    }
}

__global__ __launch_bounds__(1024) void upsample_select_kernel(
    const float* __restrict__ att, float* __restrict__ mask_out,
    unsigned long long* __restrict__ ws_bits)
{
    __shared__ float    s_in[NIN];
    __shared__ unsigned s_hist[2048];
    __shared__ unsigned s_bcast[2];

    const int b   = blockIdx.x;
    const int tid = threadIdx.x;

    const float* in = att + b * NIN;
    for (int i = tid; i < NIN; i += 1024) s_in[i] = in[i];
    __syncthreads();

    // bilinear 2x upsample, half-pixel centers; weights exactly {0.75,0.25};
    // boundary rows/cols clamp to the edge pixel. (validated absmax==0)
    unsigned ub[25];
    #pragma unroll
    for (int j = 0; j < 25; ++j) {
        int i = j * 1024 + tid;
        int r = i / 160;
        int c = i - r * 160;
        int y0, y1; float wy;
        if (r == 0)        { y0 = 0;  y1 = 0;  wy = 0.0f; }
        else if (r == 159) { y0 = 79; y1 = 79; wy = 0.0f; }
        else { float y = 0.5f * (float)r - 0.25f; y0 = (int)y; y1 = y0 + 1; wy = y - (float)y0; }
        int x0, x1; float wx;
        if (c == 0)        { x0 = 0;  x1 = 0;  wx = 0.0f; }
        else if (c == 159) { x0 = 79; x1 = 79; wx = 0.0f; }
        else { float x = 0.5f * (float)c - 0.25f; x0 = (int)x; x1 = x0 + 1; wx = x - (float)x0; }
        float top = s_in[y0 * 80 + x0] * (1.0f - wx) + s_in[y0 * 80 + x1] * wx;
        float bot = s_in[y1 * 80 + x0] * (1.0f - wx) + s_in[y1 * 80 + x1] * wx;
        float v   = top * (1.0f - wy) + bot * wy;
        ub[j] = __float_as_uint(v);   // v in [0,1) -> uint order == float order
    }

    // ---- exact radix select, 3 passes: bits [30:20], [19:10], [9:0] ----
    for (int i = tid; i < 2048; i += 1024) s_hist[i] = 0;
    __syncthreads();
    #pragma unroll
    for (int j = 0; j < 25; ++j) atomicAdd(&s_hist[ub[j] >> 20], 1u);  // <0x3F8 < 2048
    __syncthreads();
    find_bin<2048>(s_hist, KRANK, s_bcast, tid);
    __syncthreads();
    const unsigned p1  = s_bcast[0];
    unsigned       rem = s_bcast[1];
    __syncthreads();

    for (int i = tid; i < 1024; i += 1024) s_hist[i] = 0;
    __syncthreads();
    #pragma unroll
    for (int j = 0; j < 25; ++j) {
        unsigned u = ub[j];
        if ((u >> 20) == p1) atomicAdd(&s_hist[(u >> 10) & 1023u], 1u);
    }
    __syncthreads();
    find_bin<1024>(s_hist, rem, s_bcast, tid);
    __syncthreads();
    const unsigned pref2 = (p1 << 10) | s_bcast[0];
    rem = s_bcast[1];
    __syncthreads();

    for (int i = tid; i < 1024; i += 1024) s_hist[i] = 0;
    __syncthreads();
    #pragma unroll
    for (int j = 0; j < 25; ++j) {
        unsigned u = ub[j];
        if ((u >> 10) == pref2) atomicAdd(&s_hist[u & 1023u], 1u);
    }
    __syncthreads();
    find_bin<1024>(s_hist, rem, s_bcast, tid);
    __syncthreads();
    const unsigned thr_bits = (pref2 << 10) | s_bcast[0];

    // mask outputs: fp32 plane (required output) + bit-packed plane (for the
    // streaming kernel). Same values, same >= comparison -> identical set.
    float*              mptr  = mask_out + b * NUP;
    unsigned long long* wbptr = ws_bits + b * 400;   // 400 ull = 25600 bits
    const int lane = tid & 63;
    const int wv   = tid >> 6;
    #pragma unroll
    for (int j = 0; j < 25; ++j) {
        const bool sel = (ub[j] >= thr_bits);
        mptr[j * 1024 + tid] = sel ? 1.0f : 0.0f;
        unsigned long long bal = __ballot(sel);     // bit i = element j*1024+wv*64+i
        if (lane == 0) wbptr[j * 16 + wv] = bal;
    }
}

// weighted = local_feat * (mask + 0.1).
// One block per (b,c) plane; plane's bit-packed mask preloaded into LDS
// (3.2 KB). PLAIN load + PLAIN store this round (A/B vs round-7's nt load:
// nt-store was a measured -7 us regression, testing whether nt-load is too).
__global__ __launch_bounds__(256) void apply_mask_kernel(
    const f32x4* __restrict__ feat, const unsigned* __restrict__ bits,
    f32x4* __restrict__ out)
{
    __shared__ unsigned s_bits[800];

    const int tid   = threadIdx.x;
    const int plane = blockIdx.x;          // b*256 + c
    const int b     = plane >> 8;

    const unsigned* gb = bits + b * 800;
    #pragma unroll
    for (int k = 0; k < 3; ++k) s_bits[tid + k * 256] = gb[tid + k * 256];
    if (tid < 32) s_bits[768 + tid] = gb[768 + tid];
    __syncthreads();

    const f32x4* fp = feat + plane * 6400 + tid;
    f32x4*       op = out  + plane * 6400 + tid;

    #pragma unroll 5
    for (int i = 0; i < 25; ++i) {
        const unsigned u    = (unsigned)(i * 256 + tid);       // f32x4 index in plane
        const unsigned nib  = s_bits[u >> 3] >> ((u & 7u) * 4u);
        f32x4 v = fp[i * 256];            // plain load (A/B vs round-7 nt load)
        f32x4 w;
        w.x = (nib & 1u) ? 1.1f : 0.1f;   // 1.0f+0.1f == 1.1f bitwise (0x3F8CCCCD)
        w.y = (nib & 2u) ? 1.1f : 0.1f;
        w.z = (nib & 4u) ? 1.1f : 0.1f;
        w.w = (nib & 8u) ? 1.1f : 0.1f;
        v *= w;
        op[i * 256] = v;                  // plain store (established round 7)
    }
}

extern "C" void kernel_launch(void* const* d_in, const int* in_sizes, int n_in,
                              void* d_out, int out_size, void* d_ws, size_t ws_size,
                              hipStream_t stream)
{
    const float* local_feat = (const float*)d_in[0];   // (8,256,160,160) fp32
    const float* att        = (const float*)d_in[1];   // (8,1,80,80) fp32
    // d_in[2] = spatial_scale (==2, fixed by problem shapes)

    float* out      = (float*)d_out;
    float* mask_out = out + 8 * 256 * 160 * 160;       // second output region

    upsample_select_kernel<<<8, 1024, 0, stream>>>(
        att, mask_out, (unsigned long long*)d_ws);

    apply_mask_kernel<<<2048, 256, 0, stream>>>(
        (const f32x4*)local_feat, (const unsigned*)d_ws, (f32x4*)out);
}

// Round 9
// 96.131 us; speedup vs baseline: 1.2654x; 1.2654x over previous
//
#include <hip/hip_runtime.h>

// RegionSelection: bilinear 2x upsample of attention map (8,1,80,80)->(8,1,160,160),
// per-batch rank-1921 threshold (k=int(0.3*6400)=1920, threshold=topv[:,k]),
// mask = up >= thr, weighted = local_feat*(mask+0.1).
// Outputs concatenated: weighted (8*256*160*160 fp32) then mask (8*160*160 fp32).
// d_ws: bit-packed mask, 400 ull per batch (1 bit per upsampled element).

#define NIN   6400    // 80*80
#define NUP   25600   // 160*160
#define KRANK 1921u   // (k+1)-th largest == topv[:, k]

typedef float f32x4 __attribute__((ext_vector_type(4)));

// Wave-parallel "find bin containing rank `rem_in` counting from the top" over
// NBINS bins. Two-level: 64 chunk sums + shfl suffix-scan, then a parallel
// scan of the selected chunk. Executed by wave 0; result -> s_bcast.
template <int NBINS>
__device__ inline void find_bin(const unsigned* s_hist, unsigned rem_in,
                                unsigned* s_bcast, int tid)
{
    constexpr int CHUNK = NBINS / 64;
    if (tid < 64) {
        const int lane = tid;
        unsigned csum = 0;
        #pragma unroll
        for (int k = 0; k < CHUNK; ++k) csum += s_hist[lane * CHUNK + k];
        unsigned suff = csum;
        #pragma unroll
        for (int off = 1; off < 64; off <<= 1) {
            unsigned o = __shfl_down(suff, off);
            if (lane + off < 64) suff += o;
        }
        unsigned suff_next = __shfl_down(suff, 1);
        if (lane == 63) suff_next = 0;
        const bool hit = (suff >= rem_in) & (suff_next < rem_in);
        unsigned long long bmask = __ballot(hit);
        const int src = (int)__builtin_ctzll(bmask);
        const unsigned r_chunk = __shfl(rem_in - suff_next, src);
        const int      cbase   = src * CHUNK;
        unsigned h = (lane < CHUNK) ? s_hist[cbase + lane] : 0u;
        unsigned ssum = h;
        #pragma unroll
        for (int off = 1; off < CHUNK; off <<= 1) {
            unsigned o = __shfl_down(ssum, off);
            if (lane + off < CHUNK) ssum += o;
        }
        unsigned ssum_next = __shfl_down(ssum, 1);
        if (lane >= CHUNK - 1) ssum_next = 0;
        const bool hit2 = (lane < CHUNK) & (ssum >= r_chunk) & (ssum_next < r_chunk);
        if (hit2) {
            s_bcast[0] = (unsigned)(cbase + lane);
            s_bcast[1] = r_chunk - ssum_next;
        }
    }
}

// Same, over the SUM of two 4096-bin sub-histograms (wave-parity split).
__device__ inline void find_bin_4096x2(const unsigned* h0, const unsigned* h1,
                                       unsigned rem_in, unsigned* s_bcast, int tid)
{
    if (tid < 64) {
        const int lane = tid;
        unsigned csum = 0;
        #pragma unroll
        for (int k = 0; k < 64; ++k) {
            const int idx = lane * 64 + k;
            csum += h0[idx] + h1[idx];
        }
        unsigned suff = csum;
        #pragma unroll
        for (int off = 1; off < 64; off <<= 1) {
            unsigned o = __shfl_down(suff, off);
            if (lane + off < 64) suff += o;
        }
        unsigned suff_next = __shfl_down(suff, 1);
        if (lane == 63) suff_next = 0;
        const bool hit = (suff >= rem_in) & (suff_next < rem_in);
        unsigned long long bmask = __ballot(hit);
        const int src = (int)__builtin_ctzll(bmask);
        const unsigned r_chunk = __shfl(rem_in - suff_next, src);
        const int      cbase   = src * 64;
        unsigned hsum = h0[cbase + lane] + h1[cbase + lane];
        unsigned ssum = hsum;
        #pragma unroll
        for (int off = 1; off < 64; off <<= 1) {
            unsigned o = __shfl_down(ssum, off);
            if (lane + off < 64) ssum += o;
        }
        unsigned ssum_next = __shfl_down(ssum, 1);
        if (lane == 63) ssum_next = 0;
        const bool hit2 = (ssum >= r_chunk) & (ssum_next < r_chunk);
        if (hit2) {
            s_bcast[0] = (unsigned)(cbase + lane);
            s_bcast[1] = r_chunk - ssum_next;
        }
    }
}

__global__ __launch_bounds__(1024) void upsample_select_kernel(
    const float* __restrict__ att, float* __restrict__ mask_out,
    unsigned long long* __restrict__ ws_bits)
{
    __shared__ float    s_in[NIN];
    __shared__ unsigned s_hist[8192];    // 2 x 4096 sub-histograms (pass 1)
    __shared__ unsigned s_bcast[2];

    const int b   = blockIdx.x;
    const int tid = threadIdx.x;

    const float* in = att + b * NIN;
    for (int i = tid; i < NIN; i += 1024) s_in[i] = in[i];
    __syncthreads();

    // bilinear 2x upsample, half-pixel centers; weights exactly {0.75,0.25};
    // boundary rows/cols clamp to the edge pixel. (validated absmax==0)
    unsigned ub[25];
    #pragma unroll
    for (int j = 0; j < 25; ++j) {
        int i = j * 1024 + tid;
        int r = i / 160;
        int c = i - r * 160;
        int y0, y1; float wy;
        if (r == 0)        { y0 = 0;  y1 = 0;  wy = 0.0f; }
        else if (r == 159) { y0 = 79; y1 = 79; wy = 0.0f; }
        else { float y = 0.5f * (float)r - 0.25f; y0 = (int)y; y1 = y0 + 1; wy = y - (float)y0; }
        int x0, x1; float wx;
        if (c == 0)        { x0 = 0;  x1 = 0;  wx = 0.0f; }
        else if (c == 159) { x0 = 79; x1 = 79; wx = 0.0f; }
        else { float x = 0.5f * (float)c - 0.25f; x0 = (int)x; x1 = x0 + 1; wx = x - (float)x0; }
        float top = s_in[y0 * 80 + x0] * (1.0f - wx) + s_in[y0 * 80 + x1] * wx;
        float bot = s_in[y1 * 80 + x0] * (1.0f - wx) + s_in[y1 * 80 + x1] * wx;
        float v   = top * (1.0f - wy) + bot * wy;
        ub[j] = __float_as_uint(v);   // v in [0,1) -> uint order == float order
    }

    // ---- exact radix select, 3 passes: bits [30:19], [18:9], [8:0] ----
    // Pass 1: 4096 bins x 2 wave-parity sub-histograms (uniform [0,1) data
    // puts ~800 values in each hot bin; the split halves serialization).
    unsigned* myh = s_hist + ((tid >> 6) & 1) * 4096;
    for (int i = tid; i < 8192; i += 1024) s_hist[i] = 0;
    __syncthreads();
    #pragma unroll
    for (int j = 0; j < 25; ++j) atomicAdd(&myh[ub[j] >> 19], 1u);  // < 4096
    __syncthreads();
    find_bin_4096x2(s_hist, s_hist + 4096, KRANK, s_bcast, tid);
    __syncthreads();
    const unsigned p1  = s_bcast[0];
    unsigned       rem = s_bcast[1];
    __syncthreads();

    // Pass 2: filter bits[30:19]==p1, bin by bits[18:9] (1024 bins)
    for (int i = tid; i < 1024; i += 1024) s_hist[i] = 0;
    __syncthreads();
    #pragma unroll
    for (int j = 0; j < 25; ++j) {
        unsigned u = ub[j];
        if ((u >> 19) == p1) atomicAdd(&s_hist[(u >> 9) & 1023u], 1u);
    }
    __syncthreads();
    find_bin<1024>(s_hist, rem, s_bcast, tid);
    __syncthreads();
    const unsigned pref2 = (p1 << 10) | s_bcast[0];    // bits [30:9]
    rem = s_bcast[1];
    __syncthreads();

    // Pass 3: filter bits[30:9]==pref2, bin by bits[8:0] (512 bins)
    for (int i = tid; i < 512; i += 1024) s_hist[i] = 0;
    __syncthreads();
    #pragma unroll
    for (int j = 0; j < 25; ++j) {
        unsigned u = ub[j];
        if ((u >> 9) == pref2) atomicAdd(&s_hist[u & 511u], 1u);
    }
    __syncthreads();
    find_bin<512>(s_hist, rem, s_bcast, tid);
    __syncthreads();
    const unsigned thr_bits = (pref2 << 9) | s_bcast[0];

    // mask outputs: fp32 plane (required output) + bit-packed plane (for the
    // streaming kernel). Same values, same >= comparison -> identical set.
    float*              mptr  = mask_out + b * NUP;
    unsigned long long* wbptr = ws_bits + b * 400;   // 400 ull = 25600 bits
    const int lane = tid & 63;
    const int wv   = tid >> 6;
    #pragma unroll
    for (int j = 0; j < 25; ++j) {
        const bool sel = (ub[j] >= thr_bits);
        mptr[j * 1024 + tid] = sel ? 1.0f : 0.0f;
        unsigned long long bal = __ballot(sel);     // bit i = element j*1024+wv*64+i
        if (lane == 0) wbptr[j * 16 + wv] = bal;
    }
}

// weighted = local_feat * (mask + 0.1).
// One block per (b,c) plane; plane's bit-packed mask preloaded into LDS
// (3.2 KB). ESTABLISHED (r6/r7/r8 A/B): nt LOAD (keeps 200MB read stream out
// of L2, +25us) + PLAIN store (L2 writeback path, +7us vs nt store).
__global__ __launch_bounds__(256) void apply_mask_kernel(
    const f32x4* __restrict__ feat, const unsigned* __restrict__ bits,
    f32x4* __restrict__ out)
{
    __shared__ unsigned s_bits[800];

    const int tid   = threadIdx.x;
    const int plane = blockIdx.x;          // b*256 + c
    const int b     = plane >> 8;

    const unsigned* gb = bits + b * 800;
    #pragma unroll
    for (int k = 0; k < 3; ++k) s_bits[tid + k * 256] = gb[tid + k * 256];
    if (tid < 32) s_bits[768 + tid] = gb[768 + tid];
    __syncthreads();

    const f32x4* fp = feat + plane * 6400 + tid;
    f32x4*       op = out  + plane * 6400 + tid;

    #pragma unroll 5
    for (int i = 0; i < 25; ++i) {
        const unsigned u    = (unsigned)(i * 256 + tid);       // f32x4 index in plane
        const unsigned nib  = s_bits[u >> 3] >> ((u & 7u) * 4u);
        f32x4 v = __builtin_nontemporal_load(fp + i * 256);
        f32x4 w;
        w.x = (nib & 1u) ? 1.1f : 0.1f;   // 1.0f+0.1f == 1.1f bitwise (0x3F8CCCCD)
        w.y = (nib & 2u) ? 1.1f : 0.1f;
        w.z = (nib & 4u) ? 1.1f : 0.1f;
        w.w = (nib & 8u) ? 1.1f : 0.1f;
        v *= w;
        op[i * 256] = v;                  // plain store
    }
}

extern "C" void kernel_launch(void* const* d_in, const int* in_sizes, int n_in,
                              void* d_out, int out_size, void* d_ws, size_t ws_size,
                              hipStream_t stream)
{
    const float* local_feat = (const float*)d_in[0];   // (8,256,160,160) fp32
    const float* att        = (const float*)d_in[1];   // (8,1,80,80) fp32
    // d_in[2] = spatial_scale (==2, fixed by problem shapes)

    float* out      = (float*)d_out;
    float* mask_out = out + 8 * 256 * 160 * 160;       // second output region

    upsample_select_kernel<<<8, 1024, 0, stream>>>(
        att, mask_out, (unsigned long long*)d_ws);

    apply_mask_kernel<<<2048, 256, 0, stream>>>(
        (const f32x4*)local_feat, (const unsigned*)d_ws, (f32x4*)out);
}

// Round 10
// 86.297 us; speedup vs baseline: 1.4096x; 1.1140x over previous
//
#include <hip/hip_runtime.h>

// RegionSelection: bilinear 2x upsample of attention map (8,1,80,80)->(8,1,160,160),
// per-batch rank-1921 threshold (k=int(0.3*6400)=1920, threshold=topv[:,k]),
// mask = up >= thr, weighted = local_feat*(mask+0.1).
// Outputs concatenated: weighted (8*256*160*160 fp32) then mask (8*160*160 fp32).
// d_ws: bit-packed mask, 400 ull per batch (1 bit per upsampled element).

#define NIN   6400    // 80*80
#define NUP   25600   // 160*160
#define KRANK 1921u   // (k+1)-th largest == topv[:, k]

typedef float f32x4 __attribute__((ext_vector_type(4)));

// Wave-parallel "find bin containing rank `rem_in` counting from the top" over
// NBINS bins. Two-level: 64 chunk sums + shfl suffix-scan, then a parallel
// scan of the selected chunk. Executed by wave 0; result -> s_bcast.
template <int NBINS>
__device__ inline void find_bin(const unsigned* s_hist, unsigned rem_in,
                                unsigned* s_bcast, int tid)
{
    constexpr int CHUNK = NBINS / 64;
    if (tid < 64) {
        const int lane = tid;
        unsigned csum = 0;
        #pragma unroll
        for (int k = 0; k < CHUNK; ++k) csum += s_hist[lane * CHUNK + k];
        unsigned suff = csum;
        #pragma unroll
        for (int off = 1; off < 64; off <<= 1) {
            unsigned o = __shfl_down(suff, off);
            if (lane + off < 64) suff += o;
        }
        unsigned suff_next = __shfl_down(suff, 1);
        if (lane == 63) suff_next = 0;
        const bool hit = (suff >= rem_in) & (suff_next < rem_in);
        unsigned long long bmask = __ballot(hit);
        const int src = (int)__builtin_ctzll(bmask);
        const unsigned r_chunk = __shfl(rem_in - suff_next, src);
        const int      cbase   = src * CHUNK;
        unsigned h = (lane < CHUNK) ? s_hist[cbase + lane] : 0u;
        unsigned ssum = h;
        #pragma unroll
        for (int off = 1; off < CHUNK; off <<= 1) {
            unsigned o = __shfl_down(ssum, off);
            if (lane + off < CHUNK) ssum += o;
        }
        unsigned ssum_next = __shfl_down(ssum, 1);
        if (lane >= CHUNK - 1) ssum_next = 0;
        const bool hit2 = (lane < CHUNK) & (ssum >= r_chunk) & (ssum_next < r_chunk);
        if (hit2) {
            s_bcast[0] = (unsigned)(cbase + lane);
            s_bcast[1] = r_chunk - ssum_next;
        }
    }
}

// Same, over the SUM of two 4096-bin sub-histograms (wave-parity split).
__device__ inline void find_bin_4096x2(const unsigned* h0, const unsigned* h1,
                                       unsigned rem_in, unsigned* s_bcast, int tid)
{
    if (tid < 64) {
        const int lane = tid;
        unsigned csum = 0;
        #pragma unroll
        for (int k = 0; k < 64; ++k) {
            const int idx = lane * 64 + k;
            csum += h0[idx] + h1[idx];
        }
        unsigned suff = csum;
        #pragma unroll
        for (int off = 1; off < 64; off <<= 1) {
            unsigned o = __shfl_down(suff, off);
            if (lane + off < 64) suff += o;
        }
        unsigned suff_next = __shfl_down(suff, 1);
        if (lane == 63) suff_next = 0;
        const bool hit = (suff >= rem_in) & (suff_next < rem_in);
        unsigned long long bmask = __ballot(hit);
        const int src = (int)__builtin_ctzll(bmask);
        const unsigned r_chunk = __shfl(rem_in - suff_next, src);
        const int      cbase   = src * 64;
        unsigned hsum = h0[cbase + lane] + h1[cbase + lane];
        unsigned ssum = hsum;
        #pragma unroll
        for (int off = 1; off < 64; off <<= 1) {
            unsigned o = __shfl_down(ssum, off);
            if (lane + off < 64) ssum += o;
        }
        unsigned ssum_next = __shfl_down(ssum, 1);
        if (lane == 63) ssum_next = 0;
        const bool hit2 = (ssum >= r_chunk) & (ssum_next < r_chunk);
        if (hit2) {
            s_bcast[0] = (unsigned)(cbase + lane);
            s_bcast[1] = r_chunk - ssum_next;
        }
    }
}

__global__ __launch_bounds__(1024) void upsample_select_kernel(
    const float* __restrict__ att, float* __restrict__ mask_out,
    unsigned long long* __restrict__ ws_bits)
{
    __shared__ float    s_in[NIN + 81];  // +81: zero pad so y1/x1 overruns are safe
    __shared__ unsigned s_hist[8192];    // 2 x 4096 sub-histograms (pass 1)
    __shared__ unsigned s_bcast[2];

    const int b   = blockIdx.x;
    const int tid = threadIdx.x;

    const float* in = att + b * NIN;
    for (int i = tid; i < NIN; i += 1024) s_in[i] = in[i];
    if (tid < 81) s_in[NIN + tid] = 0.0f;
    __syncthreads();

    // Branch-free bilinear 2x upsample, half-pixel centers. Edge clamping via
    // fmaxf (low edge) and wy/wx := 0 at the high edge; out-of-row/pad reads
    // are multiplied by exactly 0.0f -> results bit-identical to the
    // branchy version validated in rounds 1-9 (absmax==0).
    unsigned ub[25];
    #pragma unroll
    for (int j = 0; j < 25; ++j) {
        int i = j * 1024 + tid;
        int r = i / 160;
        int c = i - r * 160;
        float yf = fmaxf(0.5f * (float)r - 0.25f, 0.0f);
        int   y0 = (int)yf;
        float wy = yf - (float)y0;
        wy = (y0 >= 79) ? 0.0f : wy;
        float xf = fmaxf(0.5f * (float)c - 0.25f, 0.0f);
        int   x0 = (int)xf;
        float wx = xf - (float)x0;
        wx = (x0 >= 79) ? 0.0f : wx;
        const float* p0 = &s_in[y0 * 80 + x0];
        float a00 = p0[0], a01 = p0[1];        // merge -> ds_read2_b32
        float a10 = p0[80], a11 = p0[81];
        float top = a00 * (1.0f - wx) + a01 * wx;
        float bot = a10 * (1.0f - wx) + a11 * wx;
        float v   = top * (1.0f - wy) + bot * wy;
        ub[j] = __float_as_uint(v);   // v in [0,1) -> uint order == float order
    }

    // ---- exact radix select, 3 passes: bits [30:19], [18:9], [8:0] ----
    unsigned* myh = s_hist + ((tid >> 6) & 1) * 4096;
    for (int i = tid; i < 8192; i += 1024) s_hist[i] = 0;
    __syncthreads();
    #pragma unroll
    for (int j = 0; j < 25; ++j) atomicAdd(&myh[ub[j] >> 19], 1u);  // < 4096
    __syncthreads();
    find_bin_4096x2(s_hist, s_hist + 4096, KRANK, s_bcast, tid);
    __syncthreads();
    const unsigned p1  = s_bcast[0];
    unsigned       rem = s_bcast[1];
    __syncthreads();

    for (int i = tid; i < 1024; i += 1024) s_hist[i] = 0;
    __syncthreads();
    #pragma unroll
    for (int j = 0; j < 25; ++j) {
        unsigned u = ub[j];
        if ((u >> 19) == p1) atomicAdd(&s_hist[(u >> 9) & 1023u], 1u);
    }
    __syncthreads();
    find_bin<1024>(s_hist, rem, s_bcast, tid);
    __syncthreads();
    const unsigned pref2 = (p1 << 10) | s_bcast[0];    // bits [30:9]
    rem = s_bcast[1];
    __syncthreads();

    for (int i = tid; i < 512; i += 1024) s_hist[i] = 0;
    __syncthreads();
    #pragma unroll
    for (int j = 0; j < 25; ++j) {
        unsigned u = ub[j];
        if ((u >> 9) == pref2) atomicAdd(&s_hist[u & 511u], 1u);
    }
    __syncthreads();
    find_bin<512>(s_hist, rem, s_bcast, tid);
    __syncthreads();
    const unsigned thr_bits = (pref2 << 9) | s_bcast[0];

    // mask outputs: fp32 plane (required output) + bit-packed plane (for the
    // streaming kernel). Same values, same >= comparison -> identical set.
    float*              mptr  = mask_out + b * NUP;
    unsigned long long* wbptr = ws_bits + b * 400;   // 400 ull = 25600 bits
    const int lane = tid & 63;
    const int wv   = tid >> 6;
    #pragma unroll
    for (int j = 0; j < 25; ++j) {
        const bool sel = (ub[j] >= thr_bits);
        mptr[j * 1024 + tid] = sel ? 1.0f : 0.0f;
        unsigned long long bal = __ballot(sel);     // bit i = element j*1024+wv*64+i
        if (lane == 0) wbptr[j * 16 + wv] = bal;
    }
}

// weighted = local_feat * (mask + 0.1).
// One block per (b,c) plane; bit-packed mask in LDS (3.2 KB).
// ESTABLISHED (r6/r7/r8 A/B): nt LOAD + PLAIN store is the fastest cell.
// This round: FULL unroll -- all 25 nt-loads issued up front (static indices
// -> registers), 25-deep MLP per wave to cover the ~900cyc nt-load latency.
__global__ __launch_bounds__(256) void apply_mask_kernel(
    const f32x4* __restrict__ feat, const unsigned* __restrict__ bits,
    f32x4* __restrict__ out)
{
    __shared__ unsigned s_bits[800];

    const int tid   = threadIdx.x;
    const int plane = blockIdx.x;          // b*256 + c
    const int b     = plane >> 8;

    const unsigned* gb = bits + b * 800;
    #pragma unroll
    for (int k = 0; k < 3; ++k) s_bits[tid + k * 256] = gb[tid + k * 256];
    if (tid < 32) s_bits[768 + tid] = gb[768 + tid];
    __syncthreads();

    const f32x4* fp = feat + plane * 6400 + tid;
    f32x4*       op = out  + plane * 6400 + tid;

    f32x4 v[25];
    #pragma unroll
    for (int i = 0; i < 25; ++i)
        v[i] = __builtin_nontemporal_load(fp + i * 256);

    #pragma unroll
    for (int i = 0; i < 25; ++i) {
        const unsigned u   = (unsigned)(i * 256 + tid);        // f32x4 index in plane
        const unsigned nib = s_bits[u >> 3] >> ((u & 7u) * 4u);
        f32x4 w;
        w.x = (nib & 1u) ? 1.1f : 0.1f;   // 1.0f+0.1f == 1.1f bitwise (0x3F8CCCCD)
        w.y = (nib & 2u) ? 1.1f : 0.1f;
        w.z = (nib & 4u) ? 1.1f : 0.1f;
        w.w = (nib & 8u) ? 1.1f : 0.1f;
        op[i * 256] = v[i] * w;           // plain store
    }
}

extern "C" void kernel_launch(void* const* d_in, const int* in_sizes, int n_in,
                              void* d_out, int out_size, void* d_ws, size_t ws_size,
                              hipStream_t stream)
{
    const float* local_feat = (const float*)d_in[0];   // (8,256,160,160) fp32
    const float* att        = (const float*)d_in[1];   // (8,1,80,80) fp32
    // d_in[2] = spatial_scale (==2, fixed by problem shapes)

    float* out      = (float*)d_out;
    float* mask_out = out + 8 * 256 * 160 * 160;       // second output region

    upsample_select_kernel<<<8, 1024, 0, stream>>>(
        att, mask_out, (unsigned long long*)d_ws);

    apply_mask_kernel<<<2048, 256, 0, stream>>>(
        (const f32x4*)local_feat, (const unsigned*)d_ws, (f32x4*)out);
}